// Round 1
// baseline (229.392 us; speedup 1.0000x reference)
//
#include <hip/hip_runtime.h>
#include <hip/hip_bf16.h>

#define Tn 512
#define Bn 512
#define Kn 128

typedef __bf16 bf16_t;
typedef __bf16 bf16x8 __attribute__((ext_vector_type(8)));
typedef float f32x4 __attribute__((ext_vector_type(4)));
typedef unsigned int u32;

__device__ __forceinline__ u32 pack2bf(float a, float b) {
    bf16_t ha = (bf16_t)a, hb = (bf16_t)b;
    u32 ua = (u32)__builtin_bit_cast(unsigned short, ha);
    u32 ub = (u32)__builtin_bit_cast(unsigned short, hb);
    return ua | (ub << 16);
}

// ---------------- prep: E-fragment build + numerator + out zeroing ----------------
// Fragment image layout: idx = ((((dir*4 + w)*2 + n)*4 + ks)*64 + l)*8 + e
//   k = 32*ks + 8*(l>>4) + e   (my sigma; used identically for A reads -> layout-safe)
//   j = 8*(l&15) + 2*w + n     (N-tile -> j interleave so lane's two j's are adjacent)
// dir 0: B[k][j] = exp(trans[k][j])   (forward:  v <- (v @ E) * x_t)
// dir 1: B[k][j] = exp(trans[j][k])   (backward: u <- (u * x_t) @ E^T)
__global__ void crf_prep(const float* __restrict__ em, const int* __restrict__ tags,
                         const int* __restrict__ mask, const float* __restrict__ startT,
                         const float* __restrict__ endT, const float* __restrict__ trans,
                         bf16_t* __restrict__ frags, float* __restrict__ num,
                         float* __restrict__ out)
{
    const int bid = blockIdx.x;
    const int tid = threadIdx.x;
    if (bid == Bn) {
        if (tid == 0) out[0] = 0.f;
        for (int idx = tid; idx < 2*Kn*Kn; idx += blockDim.x) {
            const int e   = idx & 7;
            const int l   = (idx >> 3) & 63;
            const int ks  = (idx >> 9) & 3;
            const int n   = (idx >> 11) & 1;
            const int w   = (idx >> 12) & 3;
            const int dir = (idx >> 14) & 1;
            const int k = 32*ks + 8*(l >> 4) + e;
            const int j = 8*(l & 15) + 2*w + n;
            const float v = (dir == 0) ? trans[k*Kn + j] : trans[j*Kn + k];
            frags[idx] = (bf16_t)__expf(v);
        }
        return;
    }
    // numerator for batch b
    const int b = bid;
    float s = 0.f;
    int cnt = 0;
    for (int t = tid; t < Tn; t += blockDim.x) {
        const int mk = mask[t*Bn + b];
        cnt += (mk != 0);
        if (t >= 1 && mk != 0) {
            const int tp = tags[(t-1)*Bn + b];
            const int tc = tags[t*Bn + b];
            s += trans[tp*Kn + tc] + em[(size_t)t*Bn*Kn + (size_t)b*Kn + tc];
        }
    }
    __shared__ float sred[128];
    __shared__ int   cred[128];
    sred[tid] = s; cred[tid] = cnt;
    __syncthreads();
    for (int off = 64; off > 0; off >>= 1) {
        if (tid < off) { sred[tid] += sred[tid+off]; cred[tid] += cred[tid+off]; }
        __syncthreads();
    }
    if (tid == 0) {
        const int t0tag = tags[b];
        const float n0 = startT[t0tag] + em[(size_t)b*Kn + t0tag];
        int seq_end = cred[0] - 1;
        if (seq_end < 0) seq_end = 0;
        const int lastTag = tags[seq_end*Bn + b];
        num[b] = n0 + sred[0] + endT[lastTag];
    }
}

// ---------------- main: linear-domain fwd/bwd recurrence ----------------
// 64 blocks: bid&1 = direction, bid>>1 = 16-batch group. 4 waves x (16 batches, 32 j-cols).
__global__ __launch_bounds__(256)
void crf_main(const float* __restrict__ em, const int* __restrict__ mask,
              const float* __restrict__ startT, const float* __restrict__ endT,
              const bf16_t* __restrict__ frags,
              float* __restrict__ vws, float* __restrict__ Cws)
{
    const int bid = blockIdx.x;
    const int dir = bid & 1;
    const int grp = bid >> 1;
    const int b0  = grp * 16;
    const int tid = threadIdx.x;
    const int w = tid >> 6;
    const int l = tid & 63;
    const int g = l >> 4;
    const int c = l & 15;
    const int j0   = 8*c + 2*w;   // this lane's column pair (j0, j0+1)
    const int rowb = 4*g;         // D rows 4g..4g+3 (batch within group)

    __shared__ __align__(16) bf16_t a_lds[2][16][136]; // 272B row stride (16B-aligned)
    __shared__ __align__(16) int klds[16];

    // E fragments resident for the whole kernel: [n-tile][k-slice]
    bf16x8 ef[2][4];
    {
        const bf16_t* fb = frags + (size_t)(dir*4 + w) * 4096;
        #pragma unroll
        for (int n = 0; n < 2; ++n)
            #pragma unroll
            for (int ks = 0; ks < 4; ++ks)
                ef[n][ks] = *reinterpret_cast<const bf16x8*>(fb + ((n*4 + ks)*64 + l)*8);
    }

    const int M  = dir ? 255 : 256;
    const int e0 = dir ? 511 : 0;
    const float* svp = dir ? endT : startT;
    const float sv0 = svp[j0], sv1 = svp[j0+1];

    f32x4 sprev0, sprev1, Cacc;
    #pragma unroll
    for (int r = 0; r < 4; ++r) {
        const float2 e2 = *reinterpret_cast<const float2*>(
            em + (size_t)e0*Bn*Kn + (size_t)(b0 + rowb + r)*Kn + j0);
        const float a0 = __expf(sv0 + e2.x);
        const float a1 = __expf(sv1 + e2.y);
        *reinterpret_cast<u32*>(&a_lds[1][rowb + r][j0]) = pack2bf(a0, a1);
        sprev0[r] = dir ? __expf(sv0) : a0;   // bwd: u_511 = exp(end); fwd: v_0
        sprev1[r] = dir ? __expf(sv1) : a1;
        Cacc[r] = 0.f;
    }

    // prefetch for iter 1
    float2 em_nxt0, em_nxt1, em_nxt2, em_nxt3;
    int4 mask_nxt;
    {
        const int tn = dir ? 511 : 1;
        const float* p = em + (size_t)tn*Bn*Kn + (size_t)(b0 + rowb)*Kn + j0;
        em_nxt0 = *reinterpret_cast<const float2*>(p);
        em_nxt1 = *reinterpret_cast<const float2*>(p + Kn);
        em_nxt2 = *reinterpret_cast<const float2*>(p + 2*Kn);
        em_nxt3 = *reinterpret_cast<const float2*>(p + 3*Kn);
        mask_nxt = *reinterpret_cast<const int4*>(mask + (size_t)tn*Bn + b0 + rowb);
    }

    for (int m = 1; m <= M; ++m) {
        const float2 emc[4] = {em_nxt0, em_nxt1, em_nxt2, em_nxt3};
        const int    mka[4] = {mask_nxt.x, mask_nxt.y, mask_nxt.z, mask_nxt.w};

        // stage 1: write a_m (iter 1 written in prologue)
        if (m >= 2) {
            #pragma unroll
            for (int r = 0; r < 4; ++r) {
                float a0 = sprev0[r], a1 = sprev1[r];
                if (dir) { a0 *= __expf(emc[r].x); a1 *= __expf(emc[r].y); } // bwd: fold x_t
                *reinterpret_cast<u32*>(&a_lds[m & 1][rowb + r][j0]) = pack2bf(a0, a1);
            }
        }
        // rescale bookkeeping: representative exponent of each row (j*=0 owner: w0,c0)
        if ((m & 3) == 0 && w == 0 && c == 0) {
            #pragma unroll
            for (int r = 0; r < 4; ++r)
                klds[rowb + r] = (int)((__float_as_uint(sprev0[r]) >> 23) & 0xFF) - 127;
        }
        __syncthreads();

        // prefetch next iter's em/mask (overlaps MFMA)
        if (m < M) {
            const int tn = dir ? 512 - (m+1) : (m+1);
            const float* p = em + (size_t)tn*Bn*Kn + (size_t)(b0 + rowb)*Kn + j0;
            em_nxt0 = *reinterpret_cast<const float2*>(p);
            em_nxt1 = *reinterpret_cast<const float2*>(p + Kn);
            em_nxt2 = *reinterpret_cast<const float2*>(p + 2*Kn);
            em_nxt3 = *reinterpret_cast<const float2*>(p + 3*Kn);
            mask_nxt = *reinterpret_cast<const int4*>(mask + (size_t)tn*Bn + b0 + rowb);
        }

        // stages 2-3: A-frag reads + 8 MFMAs (two 16x16 N-tiles, K=128)
        f32x4 acc0 = {0.f,0.f,0.f,0.f}, acc1 = {0.f,0.f,0.f,0.f};
        #pragma unroll
        for (int ks = 0; ks < 4; ++ks) {
            const bf16x8 af = *reinterpret_cast<const bf16x8*>(&a_lds[m & 1][c][32*ks + 8*g]);
            acc0 = __builtin_amdgcn_mfma_f32_16x16x32_bf16(af, ef[0][ks], acc0, 0, 0, 0);
            acc1 = __builtin_amdgcn_mfma_f32_16x16x32_bf16(af, ef[1][ks], acc1, 0, 0, 0);
        }

        // stage 4: apply pending power-of-2 rescale (exact; pure representation change)
        if ((m & 3) == 0) {
            const int4 kr = *reinterpret_cast<const int4*>(&klds[rowb]);
            const int ka[4] = {kr.x, kr.y, kr.z, kr.w};
            #pragma unroll
            for (int r = 0; r < 4; ++r) {
                const float sc = __uint_as_float((u32)(127 - ka[r]) << 23);
                acc0[r] *= sc; acc1[r] *= sc;
                sprev0[r] *= sc; sprev1[r] *= sc;
                Cacc[r] += (float)ka[r] * 0.69314718055994531f;
            }
        }

        // stage 5: select under mask; fwd folds x_t here
        #pragma unroll
        for (int r = 0; r < 4; ++r) {
            float n0, n1;
            if (dir) { n0 = acc0[r]; n1 = acc1[r]; }
            else { n0 = acc0[r] * __expf(emc[r].x); n1 = acc1[r] * __expf(emc[r].y); }
            const bool mk = (mka[r] != 0);
            sprev0[r] = mk ? n0 : sprev0[r];
            sprev1[r] = mk ? n1 : sprev1[r];
        }
    }

    // final normalize + store midpoint state
    __syncthreads();
    if (w == 0 && c == 0) {
        #pragma unroll
        for (int r = 0; r < 4; ++r)
            klds[rowb + r] = (int)((__float_as_uint(sprev0[r]) >> 23) & 0xFF) - 127;
    }
    __syncthreads();
    {
        const int4 kr = *reinterpret_cast<const int4*>(&klds[rowb]);
        const int ka[4] = {kr.x, kr.y, kr.z, kr.w};
        #pragma unroll
        for (int r = 0; r < 4; ++r) {
            const float sc = __uint_as_float((u32)(127 - ka[r]) << 23);
            const float v0 = sprev0[r] * sc;
            const float v1 = sprev1[r] * sc;
            const float Cf = Cacc[r] + (float)ka[r] * 0.69314718055994531f;
            const size_t row = (size_t)(dir*Bn + b0 + rowb + r);
            vws[row*Kn + j0]     = v0;
            vws[row*Kn + j0 + 1] = v1;
            if (w == 0 && c == 0) Cws[dir*Bn + b0 + rowb + r] = Cf;
        }
    }
}

// ---------------- combine: den = Cf + Cb + log(v . u); out += num - den ----------------
__global__ void crf_combine(const float* __restrict__ vws, const float* __restrict__ Cws,
                            const float* __restrict__ num, float* __restrict__ out)
{
    const int b = blockIdx.x;
    const int tid = threadIdx.x;
    const float p = vws[(size_t)b*Kn + tid] * vws[(size_t)(Bn + b)*Kn + tid];
    __shared__ float red[128];
    red[tid] = p;
    __syncthreads();
    for (int off = 64; off > 0; off >>= 1) {
        if (tid < off) red[tid] += red[tid + off];
        __syncthreads();
    }
    if (tid == 0) {
        const float den = Cws[b] + Cws[Bn + b] + logf(red[0]);
        atomicAdd(out, num[b] - den);
    }
}

extern "C" void kernel_launch(void* const* d_in, const int* in_sizes, int n_in,
                              void* d_out, int out_size, void* d_ws, size_t ws_size,
                              hipStream_t stream)
{
    const float* em     = (const float*)d_in[0];
    const int*   tags   = (const int*)d_in[1];
    const int*   mask   = (const int*)d_in[2];
    const float* startT = (const float*)d_in[3];
    const float* endT   = (const float*)d_in[4];
    const float* trans  = (const float*)d_in[5];

    char* ws = (char*)d_ws;
    bf16_t* frags = (bf16_t*)ws;                        // 65536 B
    float*  num   = (float*)(ws + 65536);               // 2048 B
    float*  Cws   = (float*)(ws + 65536 + 2048);        // 4096 B
    float*  vws   = (float*)(ws + 65536 + 2048 + 4096); // 524288 B
    float*  out   = (float*)d_out;

    hipLaunchKernelGGL(crf_prep, dim3(Bn + 1), dim3(128), 0, stream,
                       em, tags, mask, startT, endT, trans, frags, num, out);
    hipLaunchKernelGGL(crf_main, dim3(64), dim3(256), 0, stream,
                       em, mask, startT, endT, frags, vws, Cws);
    hipLaunchKernelGGL(crf_combine, dim3(Bn), dim3(128), 0, stream,
                       vws, Cws, num, out);
}